// Round 9
// baseline (98.145 us; speedup 1.0000x reference)
//
#include <hip/hip_runtime.h>

#define EPSF 1e-8f
#define DIM 256
#define SET_LEN 50
#define NUM_SETS 8192
#define BATCH 131072

#define LOG2E 1.4426950408889634f
#define LN2   0.6931471805599453f
#define EPS2  1.4426950409e-8f      /* EPSF / LN2 */
#define CPD  -0.5287663729448977f   /* log2(LN2)  */

#define QSCALE 100.0f
#define QINV   0.01f
#define Q2E    (QINV * LOG2E)       /* int-domain -> exp2 argument */
#define LUTOFF 204                  /* q in [-204, 306] -> idx in [0, 510] */
#define LUTSZ  512

#define PPW 16                      /* pairs per wave */
#define NPAIRBLK (BATCH / (PPW * 4))  /* 2048 pair blocks */

__device__ __forceinline__ float fast_exp2(float x) {
#if __has_builtin(__builtin_amdgcn_exp2f)
    return __builtin_amdgcn_exp2f(x);
#else
    return exp2f(x);
#endif
}
__device__ __forceinline__ float fast_log2(float x) {
#if __has_builtin(__builtin_amdgcn_logf)
    return __builtin_amdgcn_logf(x);
#else
    return __log2f(x);
#endif
}

// lsp2(x) = log2( log2(1 + 2^(x*log2e)) + EPS2 )
// so that  ln(softplus(x) + EPS) == LN2 * (CPD + lsp2(x))   (exact algebra)
__device__ __forceinline__ float lsp2(float x) {
    float e = fast_exp2(x * LOG2E);
    float s = fast_log2(1.0f + e);
    return fast_log2(s + EPS2);
}
__device__ __forceinline__ float lsp2q(int q) {
    float e = fast_exp2((float)q * Q2E);
    float s = fast_log2(1.0f + e);
    return fast_log2(s + EPS2);
}

__device__ __forceinline__ float wave_reduce_sum(float v) {
    #pragma unroll
    for (int off = 32; off > 0; off >>= 1) v += __shfl_xor(v, off, 64);
    return v;
}

__device__ __forceinline__ unsigned short f32_to_bf16(float f) {
    unsigned int u = __float_as_uint(f);
    unsigned int r = (u + 0x7fffu + ((u >> 16) & 1u)) >> 16;   // RNE
    return (unsigned short)r;
}
__device__ __forceinline__ float dot4(float4 a, float4 b) {
    return a.x*b.x + a.y*b.y + a.z*b.z + a.w*b.w;
}
__device__ __forceinline__ signed char quant8(float v) {
    int q = (int)rintf(v * QSCALE);
    q = max(-127, min(127, q));
    return (signed char)q;
}
__device__ __forceinline__ float4 f4_axpby(float4 e, float a, float4 x, float w) {
    // e*a + x*w
    float4 r;
    r.x = fmaf(e.x, a, x.x * w);
    r.y = fmaf(e.y, a, x.y * w);
    r.z = fmaf(e.z, a, x.z * w);
    r.w = fmaf(e.w, a, x.w * w);
    return r;
}
__device__ __forceinline__ float4 shfl_xor_f4(float4 v, int off) {
    float4 r;
    r.x = __shfl_xor(v.x, off, 64);
    r.y = __shfl_xor(v.y, off, 64);
    r.z = __shfl_xor(v.z, off, 64);
    r.w = __shfl_xor(v.w, off, 64);
    return r;
}

// One block (256 threads) per set. Ballot-compacted active rows. ONLINE
// softmax: each 16-lane group streams rows once (8 indep float4 loads/row),
// maintaining running (m, s, E[256-across-16-lanes]) per table. No row
// staging, no second pass -> LDS ~8.5 KB, continuous load stream.
__global__ __launch_bounds__(256) void attn_kernel(
    const int* __restrict__ S, const int* __restrict__ M,
    const float* __restrict__ Xc, const float* __restrict__ Xr,
    const float* __restrict__ Ac, const float* __restrict__ Ar,
    signed char* __restrict__ emb_q, float* __restrict__ bv)
{
    const int s    = blockIdx.x;
    const int tid  = threadIdx.x;
    const int lane = tid & 63;
    const int wid  = tid >> 6;
    const int g    = lane >> 4;   // row-group 0..3 within wave
    const int sl   = lane & 15;   // sub-lane 0..15

    __shared__ int   sh_act[SET_LEN];
    __shared__ int   sh_nact;
    __shared__ float sh_scale;
    __shared__ float Ec_l[4][DIM];   // 4 KB
    __shared__ float Er_l[4][DIM];   // 4 KB
    __shared__ float m4c[4], s4c[4], m4r[4], s4r[4];
    __shared__ float sh_red[4];

    // wave 0: load indices/mask, ballot-compact active rows
    if (wid == 0) {
        int idx = 0, m = 0;
        if (lane < SET_LEN) {
            idx = S[s * SET_LEN + lane];
            m   = M[s * SET_LEN + lane];
        }
        unsigned long long bal = __ballot(m != 0);
        int rank = __popcll(bal & ((1ull << lane) - 1ull));
        if (m) sh_act[rank] = idx;
        if (lane == 0) {
            int n = __popcll(bal);
            sh_nact = n;
            sh_scale = (n > 0) ? exp2f(log2f((float)n) * (1.0f / DIM)) : 0.0f;
        }
    }
    __syncthreads();
    const int nact = sh_nact;

    // per-lane A fragments: chunk c covers float4 index c*16+sl
    float4 afc[4], afr[4];
    #pragma unroll
    for (int c = 0; c < 4; ++c) {
        afc[c] = ((const float4*)Ac)[c * 16 + sl];
        afr[c] = ((const float4*)Ar)[c * 16 + sl];
    }

    // online-softmax state per group (per table)
    float mc = -1e30f, sc = 0.0f, mr = -1e30f, sr = 0.0f;
    float4 Ec[4], Er[4];
    #pragma unroll
    for (int c = 0; c < 4; ++c) {
        Ec[c] = make_float4(0.f, 0.f, 0.f, 0.f);
        Er[c] = make_float4(0.f, 0.f, 0.f, 0.f);
    }

    for (int k = wid * 4 + g; k < nact; k += 16) {
        const size_t row = (size_t)sh_act[k] * DIM;
        const float4* xc = (const float4*)(Xc + row);
        const float4* xr = (const float4*)(Xr + row);
        float4 c0 = xc[sl], c1 = xc[16 + sl], c2 = xc[32 + sl], c3 = xc[48 + sl];
        float4 r0 = xr[sl], r1 = xr[16 + sl], r2 = xr[32 + sl], r3 = xr[48 + sl];

        float pc = dot4(c0, afc[0]) + dot4(c1, afc[1]) + dot4(c2, afc[2]) + dot4(c3, afc[3]);
        float pr = dot4(r0, afr[0]) + dot4(r1, afr[1]) + dot4(r2, afr[2]) + dot4(r3, afr[3]);
        #pragma unroll
        for (int off = 8; off > 0; off >>= 1) {
            pc += __shfl_xor(pc, off, 64);
            pr += __shfl_xor(pr, off, 64);
        }

        // center: rescale-and-accumulate
        {
            float mn = fmaxf(mc, pc);
            float rs = fast_exp2((mc - mn) * LOG2E);
            float w  = fast_exp2((pc - mn) * LOG2E);
            sc = fmaf(sc, rs, w);
            Ec[0] = f4_axpby(Ec[0], rs, c0, w);
            Ec[1] = f4_axpby(Ec[1], rs, c1, w);
            Ec[2] = f4_axpby(Ec[2], rs, c2, w);
            Ec[3] = f4_axpby(Ec[3], rs, c3, w);
            mc = mn;
        }
        // radius
        {
            float mn = fmaxf(mr, pr);
            float rs = fast_exp2((mr - mn) * LOG2E);
            float w  = fast_exp2((pr - mn) * LOG2E);
            sr = fmaf(sr, rs, w);
            Er[0] = f4_axpby(Er[0], rs, r0, w);
            Er[1] = f4_axpby(Er[1], rs, r1, w);
            Er[2] = f4_axpby(Er[2], rs, r2, w);
            Er[3] = f4_axpby(Er[3], rs, r3, w);
            mr = mn;
        }
    }

    // merge the 4 groups of this wave (lanes sl..sl+48 hold same dims)
    #pragma unroll
    for (int off = 16; off <= 32; off <<= 1) {
        // center
        {
            float mo = __shfl_xor(mc, off, 64);
            float so = __shfl_xor(sc, off, 64);
            float mn = fmaxf(mc, mo);
            float ra = fast_exp2((mc - mn) * LOG2E);
            float rb = fast_exp2((mo - mn) * LOG2E);
            #pragma unroll
            for (int c = 0; c < 4; ++c) {
                float4 Eo = shfl_xor_f4(Ec[c], off);
                Ec[c] = f4_axpby(Ec[c], ra, Eo, rb);
            }
            sc = fmaf(sc, ra, so * rb);
            mc = mn;
        }
        // radius
        {
            float mo = __shfl_xor(mr, off, 64);
            float so = __shfl_xor(sr, off, 64);
            float mn = fmaxf(mr, mo);
            float ra = fast_exp2((mr - mn) * LOG2E);
            float rb = fast_exp2((mo - mn) * LOG2E);
            #pragma unroll
            for (int c = 0; c < 4; ++c) {
                float4 Eo = shfl_xor_f4(Er[c], off);
                Er[c] = f4_axpby(Er[c], ra, Eo, rb);
            }
            sr = fmaf(sr, ra, so * rb);
            mr = mn;
        }
    }

    // stash per-wave merged state in LDS
    if (lane < 16) {
        #pragma unroll
        for (int c = 0; c < 4; ++c) {
            ((float4*)&Ec_l[wid][0])[c * 16 + sl] = Ec[c];
            ((float4*)&Er_l[wid][0])[c * 16 + sl] = Er[c];
        }
    }
    if (lane == 0) { m4c[wid] = mc; s4c[wid] = sc; m4r[wid] = mr; s4r[wid] = sr; }
    __syncthreads();

    // final per-dim merge across the 4 waves: thread tid owns dim d = tid
    const float scale = sh_scale;
    float ec, er;
    {
        float m1 = fmaxf(fmaxf(m4c[0], m4c[1]), fmaxf(m4c[2], m4c[3]));
        float w0 = fast_exp2((m4c[0] - m1) * LOG2E);
        float w1 = fast_exp2((m4c[1] - m1) * LOG2E);
        float w2 = fast_exp2((m4c[2] - m1) * LOG2E);
        float w3 = fast_exp2((m4c[3] - m1) * LOG2E);
        float den = s4c[0]*w0 + s4c[1]*w1 + s4c[2]*w2 + s4c[3]*w3;
        float num = Ec_l[0][tid]*w0 + Ec_l[1][tid]*w1 + Ec_l[2][tid]*w2 + Ec_l[3][tid]*w3;
        ec = (den > 0.0f) ? (num / den) * scale : 0.0f;
    }
    {
        float m1 = fmaxf(fmaxf(m4r[0], m4r[1]), fmaxf(m4r[2], m4r[3]));
        float w0 = fast_exp2((m4r[0] - m1) * LOG2E);
        float w1 = fast_exp2((m4r[1] - m1) * LOG2E);
        float w2 = fast_exp2((m4r[2] - m1) * LOG2E);
        float w3 = fast_exp2((m4r[3] - m1) * LOG2E);
        float den = s4r[0]*w0 + s4r[1]*w1 + s4r[2]*w2 + s4r[3]*w3;
        float num = Er_l[0][tid]*w0 + Er_l[1][tid]*w1 + Er_l[2][tid]*w2 + Er_l[3][tid]*w3;
        er = (den > 0.0f) ? (num / den) * scale : 0.0f;
    }

    emb_q[(size_t)s * 512 + tid]       = quant8(ec);
    emb_q[(size_t)s * 512 + 256 + tid] = quant8(er);

    float term = lsp2(er);
    float wsum = wave_reduce_sum(term);
    if (lane == 0) sh_red[wid] = wsum;
    __syncthreads();
    if (tid == 0)
        bv[s] = LN2 * ((sh_red[0] + sh_red[1] + sh_red[2] + sh_red[3])
                       + (float)DIM * CPD);
}

__device__ __forceinline__ void i8x16_unpack(uint4 u, int* o) {
    unsigned int ws[4] = { u.x, u.y, u.z, u.w };
    #pragma unroll
    for (int w = 0; w < 4; ++w) {
        o[4*w+0] = (int)(signed char)(ws[w]);
        o[4*w+1] = (int)(signed char)(ws[w] >> 8);
        o[4*w+2] = (int)(signed char)(ws[w] >> 16);
        o[4*w+3] = (int)(signed char)(ws[w] >> 24);
    }
}

// int-domain box terms for 16 dims, one LDS LUT read per term.
__device__ __forceinline__ void pair_accum_lut(const float* __restrict__ lut,
                                               uint4 ac, uint4 ar, uint4 bc, uint4 br,
                                               float& it, float& ut) {
    int ci[16], ri[16], cj[16], rj[16];
    i8x16_unpack(ac, ci); i8x16_unpack(ar, ri);
    i8x16_unpack(bc, cj); i8x16_unpack(br, rj);
    #pragma unroll
    for (int k = 0; k < 16; ++k) {
        const int Mi = ci[k] + ri[k];
        const int Mj = cj[k] + rj[k];
        const int lo = min(Mi, Mj) - max(ci[k], cj[k]);
        const int hi = max(Mi, Mj) - min(ci[k], cj[k]);
        it += lut[lo + LUTOFF];
        ut += lut[hi + LUTOFF];
    }
}

// 16 lanes per pair, 4 pairs in flight per wave; int8 emb rows, LDS LUT,
// per-block partials (no atomics).
__global__ __launch_bounds__(256) void pair_kernel(
    const int* __restrict__ inst, const float* __restrict__ sims,
    const signed char* __restrict__ emb_q,
    const float* __restrict__ bv, float4* __restrict__ part)
{
    const int tid  = threadIdx.x;
    const int lane = tid & 63;
    const int wid  = tid >> 6;
    const int g    = lane >> 4;
    const int sl   = lane & 15;
    const int wave = blockIdx.x * 4 + wid;
    const int base = wave * PPW;

    __shared__ float lut[LUTSZ];
    __shared__ float sh_i[4][PPW];
    __shared__ float sh_u[4][PPW];
    __shared__ float sred[4][4];

    #pragma unroll
    for (int e = tid; e < LUTSZ; e += 256) lut[e] = lsp2q(e - LUTOFF);

    int idxreg = 0;
    if (lane < 2 * PPW) idxreg = inst[2 * base + lane];
    __syncthreads();

    uint4 a_c, a_r, b_c, b_r;
    {
        const int i = __shfl(idxreg, 2 * g);
        const int j = __shfl(idxreg, 2 * g + 1);
        const uint4* pi = (const uint4*)(emb_q + (size_t)i * 512);
        const uint4* pj = (const uint4*)(emb_q + (size_t)j * 512);
        a_c = pi[sl]; a_r = pi[16 + sl];
        b_c = pj[sl]; b_r = pj[16 + sl];
    }

    #pragma unroll
    for (int m = 0; m < 4; ++m) {
        uint4 n0, n1, n2, n3;
        if (m < 3) {
            const int slot = (m + 1) * 4 + g;
            const int i = __shfl(idxreg, 2 * slot);
            const int j = __shfl(idxreg, 2 * slot + 1);
            const uint4* pi = (const uint4*)(emb_q + (size_t)i * 512);
            const uint4* pj = (const uint4*)(emb_q + (size_t)j * 512);
            n0 = pi[sl]; n1 = pi[16 + sl];
            n2 = pj[sl]; n3 = pj[16 + sl];
        }

        float it = 0.0f, ut = 0.0f;
        pair_accum_lut(lut, a_c, a_r, b_c, b_r, it, ut);
        #pragma unroll
        for (int o = 8; o > 0; o >>= 1) {
            it += __shfl_xor(it, o, 64);
            ut += __shfl_xor(ut, o, 64);
        }
        if (sl == 0) { sh_i[wid][m * 4 + g] = it; sh_u[wid][m * 4 + g] = ut; }

        if (m < 3) { a_c = n0; a_r = n1; b_c = n2; b_r = n3; }
    }
    __syncthreads();

    float l1 = 0.0f, l2 = 0.0f, l3 = 0.0f, l4 = 0.0f;
    if (lane < PPW) {
        const int b = base + lane;
        const int i = inst[2 * b];
        const int j = inst[2 * b + 1];
        const float inter = LN2 * (sh_i[wid][lane] + (float)DIM * CPD);
        const float unn   = LN2 * (sh_u[wid][lane] + (float)DIM * CPD);
        const float bvi = bv[i], bvj = bv[j];
        const float co  = __expf(inter - fmaxf(bvi, bvj));
        const float cja = __expf(inter - unn);
        const float cco = __expf(inter - 0.5f * (bvi + bvj));
        const float cdi = 2.0f * __expf(inter) /
                          (__expf(bvi) + __expf(bvj) + EPSF);
        const float4 sm = ((const float4*)sims)[b];
        float d;
        d = co  - sm.x; l1 = d * d;
        d = cja - sm.y; l2 = d * d;
        d = cco - sm.z; l3 = d * d;
        d = cdi - sm.w; l4 = d * d;
    }
    l1 = wave_reduce_sum(l1);
    l2 = wave_reduce_sum(l2);
    l3 = wave_reduce_sum(l3);
    l4 = wave_reduce_sum(l4);

    if (lane == 0) {
        sred[wid][0] = l1; sred[wid][1] = l2;
        sred[wid][2] = l3; sred[wid][3] = l4;
    }
    __syncthreads();
    if (tid == 0) {
        float4 p;
        p.x = sred[0][0] + sred[1][0] + sred[2][0] + sred[3][0];
        p.y = sred[0][1] + sred[1][1] + sred[2][1] + sred[3][1];
        p.z = sred[0][2] + sred[1][2] + sred[2][2] + sred[3][2];
        p.w = sred[0][3] + sred[1][3] + sred[2][3] + sred[3][3];
        part[blockIdx.x] = p;
    }
}

// single-block final reduction: sum 2048 float4 partials in f64
__global__ __launch_bounds__(256) void reduce_out(
    const float4* __restrict__ part, float* __restrict__ out)
{
    const int tid  = threadIdx.x;
    const int lane = tid & 63;
    const int wid  = tid >> 6;

    double s0 = 0.0, s1 = 0.0, s2 = 0.0, s3 = 0.0;
    for (int k = tid; k < NPAIRBLK; k += 256) {
        float4 p = part[k];
        s0 += (double)p.x; s1 += (double)p.y;
        s2 += (double)p.z; s3 += (double)p.w;
    }
    #pragma unroll
    for (int off = 32; off > 0; off >>= 1) {
        s0 += __shfl_xor(s0, off, 64);
        s1 += __shfl_xor(s1, off, 64);
        s2 += __shfl_xor(s2, off, 64);
        s3 += __shfl_xor(s3, off, 64);
    }
    __shared__ double sd[4][4];
    if (lane == 0) { sd[wid][0] = s0; sd[wid][1] = s1; sd[wid][2] = s2; sd[wid][3] = s3; }
    __syncthreads();
    if (tid == 0) {
        out[0] = (float)(sd[0][0] + sd[1][0] + sd[2][0] + sd[3][0]);
        out[1] = (float)(sd[0][1] + sd[1][1] + sd[2][1] + sd[3][1]);
        out[2] = (float)(sd[0][2] + sd[1][2] + sd[2][2] + sd[3][2]);
        out[3] = (float)(sd[0][3] + sd[1][3] + sd[2][3] + sd[3][3]);
    }
}

extern "C" void kernel_launch(void* const* d_in, const int* in_sizes, int n_in,
                              void* d_out, int out_size, void* d_ws, size_t ws_size,
                              hipStream_t stream) {
    const int*   S    = (const int*)d_in[0];
    const int*   M    = (const int*)d_in[1];
    const int*   inst = (const int*)d_in[2];
    const float* sims = (const float*)d_in[3];
    const float* Xc   = (const float*)d_in[4];
    const float* Xr   = (const float*)d_in[5];
    const float* Ac   = (const float*)d_in[6];
    const float* Ar   = (const float*)d_in[7];
    float* out = (float*)d_out;

    char* ws = (char*)d_ws;
    signed char* emb_q = (signed char*)(ws);              // 8192*512 int8 = 4 MiB
    float*  bv   = (float*)(ws + 4194304);                // 32 KiB
    float4* part = (float4*)(ws + 4227072);               // 2048*16 B = 32 KiB

    attn_kernel<<<NUM_SETS, 256, 0, stream>>>(S, M, Xc, Xr, Ac, Ar, emb_q, bv);
    pair_kernel<<<NPAIRBLK, 256, 0, stream>>>(inst, sims, emb_q, bv, part);
    reduce_out<<<1, 256, 0, stream>>>(part, out);
}

// Round 10
// 94.397 us; speedup vs baseline: 1.0397x; 1.0397x over previous
//
#include <hip/hip_runtime.h>

#define EPSF 1e-8f
#define DIM 256
#define SET_LEN 50
#define NUM_SETS 8192
#define BATCH 131072

#define LOG2E 1.4426950408889634f
#define LN2   0.6931471805599453f
#define EPS2  1.4426950409e-8f      /* EPSF / LN2 */
#define CPD  -0.5287663729448977f   /* log2(LN2)  */

#define QSCALE 100.0f
#define QINV   0.01f
#define Q2E    (QINV * LOG2E)       /* int-domain -> exp2 argument */
#define LUTOFF 204                  /* q in [-204, 306] -> idx in [0, 510] */
#define LUTSZ  512

#define SSCALE 127.0f               /* LDS row-staging quant scale */
#define SINV   (1.0f / 127.0f)

#define PPW 16                      /* pairs per wave */
#define NPAIRBLK (BATCH / (PPW * 4))  /* 2048 pair blocks */

__device__ __forceinline__ float fast_exp2(float x) {
#if __has_builtin(__builtin_amdgcn_exp2f)
    return __builtin_amdgcn_exp2f(x);
#else
    return exp2f(x);
#endif
}
__device__ __forceinline__ float fast_log2(float x) {
#if __has_builtin(__builtin_amdgcn_logf)
    return __builtin_amdgcn_logf(x);
#else
    return __log2f(x);
#endif
}

// lsp2(x) = log2( log2(1 + 2^(x*log2e)) + EPS2 )
// so that  ln(softplus(x) + EPS) == LN2 * (CPD + lsp2(x))   (exact algebra)
__device__ __forceinline__ float lsp2(float x) {
    float e = fast_exp2(x * LOG2E);
    float s = fast_log2(1.0f + e);
    return fast_log2(s + EPS2);
}
__device__ __forceinline__ float lsp2q(int q) {
    float e = fast_exp2((float)q * Q2E);
    float s = fast_log2(1.0f + e);
    return fast_log2(s + EPS2);
}

__device__ __forceinline__ float wave_reduce_sum(float v) {
    #pragma unroll
    for (int off = 32; off > 0; off >>= 1) v += __shfl_xor(v, off, 64);
    return v;
}
__device__ __forceinline__ float wave_reduce_max(float v) {
    #pragma unroll
    for (int off = 32; off > 0; off >>= 1) v = fmaxf(v, __shfl_xor(v, off, 64));
    return v;
}

__device__ __forceinline__ float dot4(float4 a, float4 b) {
    return a.x*b.x + a.y*b.y + a.z*b.z + a.w*b.w;
}
__device__ __forceinline__ signed char quant8(float v) {
    int q = (int)rintf(v * QSCALE);
    q = max(-127, min(127, q));
    return (signed char)q;
}
__device__ __forceinline__ unsigned int pack_i8x4(float4 v) {
    int a = max(-127, min(127, (int)rintf(v.x * SSCALE)));
    int b = max(-127, min(127, (int)rintf(v.y * SSCALE)));
    int c = max(-127, min(127, (int)rintf(v.z * SSCALE)));
    int d = max(-127, min(127, (int)rintf(v.w * SSCALE)));
    return (unsigned int)(a & 0xff) | ((unsigned int)(b & 0xff) << 8) |
           ((unsigned int)(c & 0xff) << 16) | ((unsigned int)(d & 0xff) << 24);
}

// One block (256 threads) per set. Two-pass (R8 structure): logit pass with
// 16 lanes/row, 4 rows/wave in flight, rows staged to LDS as INT8 (scale 127)
// -> 26.6 KB LDS -> 6 blocks/CU (75% occupancy cap, vs 37.5% at bf16).
// Weighted-sum pass reads LDS only. Embeddings stored int8 (scale 100).
__global__ __launch_bounds__(256, 6) void attn_kernel(
    const int* __restrict__ S, const int* __restrict__ M,
    const float* __restrict__ Xc, const float* __restrict__ Xr,
    const float* __restrict__ Ac, const float* __restrict__ Ar,
    signed char* __restrict__ emb_q, float* __restrict__ bv)
{
    const int s    = blockIdx.x;
    const int tid  = threadIdx.x;
    const int lane = tid & 63;
    const int wid  = tid >> 6;
    const int g    = lane >> 4;   // row-group 0..3 within wave
    const int sl   = lane & 15;   // sub-lane 0..15

    __shared__ signed char shc[SET_LEN][DIM];   // 12.8 KB int8 center rows
    __shared__ signed char shr[SET_LEN][DIM];   // 12.8 KB int8 radius rows
    __shared__ int   sh_act[SET_LEN];
    __shared__ float sh_wc[SET_LEN];            // logits, overwritten by weights
    __shared__ float sh_wr[SET_LEN];
    __shared__ int   sh_nact;
    __shared__ float sh_scale;
    __shared__ float sh_red[4];

    // wave 0: load indices/mask, ballot-compact active rows
    if (wid == 0) {
        int idx = 0, m = 0;
        if (lane < SET_LEN) {
            idx = S[s * SET_LEN + lane];
            m   = M[s * SET_LEN + lane];
        }
        unsigned long long bal = __ballot(m != 0);
        int rank = __popcll(bal & ((1ull << lane) - 1ull));
        if (m) sh_act[rank] = idx;
        if (lane == 0) {
            int n = __popcll(bal);
            sh_nact = n;
            sh_scale = (n > 0) ? exp2f(log2f((float)n) * (1.0f / DIM)) : 0.0f;
        }
    }
    __syncthreads();
    const int nact = sh_nact;

    // per-lane A fragments: chunk c covers float4 index c*16+sl
    float4 afc[4], afr[4];
    #pragma unroll
    for (int c = 0; c < 4; ++c) {
        afc[c] = ((const float4*)Ac)[c * 16 + sl];
        afr[c] = ((const float4*)Ar)[c * 16 + sl];
    }

    // logit + stage pass: 16 rows per block-iter (4 waves x 4 groups)
    const int nit = (nact + 15) >> 4;
    for (int it = 0; it < nit; ++it) {
        const int k = it * 16 + wid * 4 + g;
        float pc = 0.0f, pr = 0.0f;
        if (k < nact) {
            const size_t row = (size_t)sh_act[k] * DIM;
            const float4* xc = (const float4*)(Xc + row);
            const float4* xr = (const float4*)(Xr + row);
            float4 c0 = xc[sl], c1 = xc[16 + sl], c2 = xc[32 + sl], c3 = xc[48 + sl];
            float4 r0 = xr[sl], r1 = xr[16 + sl], r2 = xr[32 + sl], r3 = xr[48 + sl];
            pc = dot4(c0, afc[0]) + dot4(c1, afc[1]) + dot4(c2, afc[2]) + dot4(c3, afc[3]);
            pr = dot4(r0, afr[0]) + dot4(r1, afr[1]) + dot4(r2, afr[2]) + dot4(r3, afr[3]);
            // stage rows to LDS as int8 (lane already holds them)
            *(unsigned int*)&shc[k][  0 + 4*sl] = pack_i8x4(c0);
            *(unsigned int*)&shc[k][ 64 + 4*sl] = pack_i8x4(c1);
            *(unsigned int*)&shc[k][128 + 4*sl] = pack_i8x4(c2);
            *(unsigned int*)&shc[k][192 + 4*sl] = pack_i8x4(c3);
            *(unsigned int*)&shr[k][  0 + 4*sl] = pack_i8x4(r0);
            *(unsigned int*)&shr[k][ 64 + 4*sl] = pack_i8x4(r1);
            *(unsigned int*)&shr[k][128 + 4*sl] = pack_i8x4(r2);
            *(unsigned int*)&shr[k][192 + 4*sl] = pack_i8x4(r3);
        }
        #pragma unroll
        for (int off = 8; off > 0; off >>= 1) {
            pc += __shfl_xor(pc, off, 64);
            pr += __shfl_xor(pr, off, 64);
        }
        if (k < nact && sl == 0) { sh_wc[k] = pc; sh_wr[k] = pr; }
    }
    __syncthreads();

    // compacted softmax in-place (logits -> weights): wave0 center, wave1 radius
    if (wid < 2) {
        float* w = (wid == 0) ? sh_wc : sh_wr;
        float v  = (lane < nact) ? w[lane] : -1e30f;
        float mx = wave_reduce_max(v);
        float p  = (lane < nact) ? __expf(v - mx) : 0.0f;
        float sm = wave_reduce_sum(p);
        float inv = (sm > 0.0f) ? (1.0f / sm) : 0.0f;
        if (lane < nact) w[lane] = p * inv;
    }
    __syncthreads();

    // weighted-sum pass entirely from LDS: thread tid owns dim d = tid
    float accc = 0.0f, accr = 0.0f;
    #pragma unroll 4
    for (int k = 0; k < nact; ++k) {
        accc = fmaf(sh_wc[k], (float)shc[k][tid], accc);
        accr = fmaf(sh_wr[k], (float)shr[k][tid], accr);
    }
    const float scale = sh_scale * SINV;   // fold 1/127 dequant into size-scale
    const float ec = accc * scale;
    const float er = accr * scale;
    emb_q[(size_t)s * 512 + tid]       = quant8(ec);
    emb_q[(size_t)s * 512 + 256 + tid] = quant8(er);

    float term = lsp2(er);
    float wsum = wave_reduce_sum(term);
    if (lane == 0) sh_red[wid] = wsum;
    __syncthreads();
    if (tid == 0)
        bv[s] = LN2 * ((sh_red[0] + sh_red[1] + sh_red[2] + sh_red[3])
                       + (float)DIM * CPD);
}

__device__ __forceinline__ void i8x16_unpack(uint4 u, int* o) {
    unsigned int ws[4] = { u.x, u.y, u.z, u.w };
    #pragma unroll
    for (int w = 0; w < 4; ++w) {
        o[4*w+0] = (int)(signed char)(ws[w]);
        o[4*w+1] = (int)(signed char)(ws[w] >> 8);
        o[4*w+2] = (int)(signed char)(ws[w] >> 16);
        o[4*w+3] = (int)(signed char)(ws[w] >> 24);
    }
}

// int-domain box terms for 16 dims, one LDS LUT read per term.
__device__ __forceinline__ void pair_accum_lut(const float* __restrict__ lut,
                                               uint4 ac, uint4 ar, uint4 bc, uint4 br,
                                               float& it, float& ut) {
    int ci[16], ri[16], cj[16], rj[16];
    i8x16_unpack(ac, ci); i8x16_unpack(ar, ri);
    i8x16_unpack(bc, cj); i8x16_unpack(br, rj);
    #pragma unroll
    for (int k = 0; k < 16; ++k) {
        const int Mi = ci[k] + ri[k];
        const int Mj = cj[k] + rj[k];
        const int lo = min(Mi, Mj) - max(ci[k], cj[k]);
        const int hi = max(Mi, Mj) - min(ci[k], cj[k]);
        it += lut[lo + LUTOFF];
        ut += lut[hi + LUTOFF];
    }
}

// 16 lanes per pair, 4 pairs in flight per wave; int8 emb rows, LDS LUT,
// per-block partials (no atomics).
__global__ __launch_bounds__(256) void pair_kernel(
    const int* __restrict__ inst, const float* __restrict__ sims,
    const signed char* __restrict__ emb_q,
    const float* __restrict__ bv, float4* __restrict__ part)
{
    const int tid  = threadIdx.x;
    const int lane = tid & 63;
    const int wid  = tid >> 6;
    const int g    = lane >> 4;
    const int sl   = lane & 15;
    const int wave = blockIdx.x * 4 + wid;
    const int base = wave * PPW;

    __shared__ float lut[LUTSZ];
    __shared__ float sh_i[4][PPW];
    __shared__ float sh_u[4][PPW];
    __shared__ float sred[4][4];

    #pragma unroll
    for (int e = tid; e < LUTSZ; e += 256) lut[e] = lsp2q(e - LUTOFF);

    int idxreg = 0;
    if (lane < 2 * PPW) idxreg = inst[2 * base + lane];
    __syncthreads();

    uint4 a_c, a_r, b_c, b_r;
    {
        const int i = __shfl(idxreg, 2 * g);
        const int j = __shfl(idxreg, 2 * g + 1);
        const uint4* pi = (const uint4*)(emb_q + (size_t)i * 512);
        const uint4* pj = (const uint4*)(emb_q + (size_t)j * 512);
        a_c = pi[sl]; a_r = pi[16 + sl];
        b_c = pj[sl]; b_r = pj[16 + sl];
    }

    #pragma unroll
    for (int m = 0; m < 4; ++m) {
        uint4 n0, n1, n2, n3;
        if (m < 3) {
            const int slot = (m + 1) * 4 + g;
            const int i = __shfl(idxreg, 2 * slot);
            const int j = __shfl(idxreg, 2 * slot + 1);
            const uint4* pi = (const uint4*)(emb_q + (size_t)i * 512);
            const uint4* pj = (const uint4*)(emb_q + (size_t)j * 512);
            n0 = pi[sl]; n1 = pi[16 + sl];
            n2 = pj[sl]; n3 = pj[16 + sl];
        }

        float it = 0.0f, ut = 0.0f;
        pair_accum_lut(lut, a_c, a_r, b_c, b_r, it, ut);
        #pragma unroll
        for (int o = 8; o > 0; o >>= 1) {
            it += __shfl_xor(it, o, 64);
            ut += __shfl_xor(ut, o, 64);
        }
        if (sl == 0) { sh_i[wid][m * 4 + g] = it; sh_u[wid][m * 4 + g] = ut; }

        if (m < 3) { a_c = n0; a_r = n1; b_c = n2; b_r = n3; }
    }
    __syncthreads();

    float l1 = 0.0f, l2 = 0.0f, l3 = 0.0f, l4 = 0.0f;
    if (lane < PPW) {
        const int b = base + lane;
        const int i = inst[2 * b];
        const int j = inst[2 * b + 1];
        const float inter = LN2 * (sh_i[wid][lane] + (float)DIM * CPD);
        const float unn   = LN2 * (sh_u[wid][lane] + (float)DIM * CPD);
        const float bvi = bv[i], bvj = bv[j];
        const float co  = __expf(inter - fmaxf(bvi, bvj));
        const float cja = __expf(inter - unn);
        const float cco = __expf(inter - 0.5f * (bvi + bvj));
        const float cdi = 2.0f * __expf(inter) /
                          (__expf(bvi) + __expf(bvj) + EPSF);
        const float4 sm = ((const float4*)sims)[b];
        float d;
        d = co  - sm.x; l1 = d * d;
        d = cja - sm.y; l2 = d * d;
        d = cco - sm.z; l3 = d * d;
        d = cdi - sm.w; l4 = d * d;
    }
    l1 = wave_reduce_sum(l1);
    l2 = wave_reduce_sum(l2);
    l3 = wave_reduce_sum(l3);
    l4 = wave_reduce_sum(l4);

    if (lane == 0) {
        sred[wid][0] = l1; sred[wid][1] = l2;
        sred[wid][2] = l3; sred[wid][3] = l4;
    }
    __syncthreads();
    if (tid == 0) {
        float4 p;
        p.x = sred[0][0] + sred[1][0] + sred[2][0] + sred[3][0];
        p.y = sred[0][1] + sred[1][1] + sred[2][1] + sred[3][1];
        p.z = sred[0][2] + sred[1][2] + sred[2][2] + sred[3][2];
        p.w = sred[0][3] + sred[1][3] + sred[2][3] + sred[3][3];
        part[blockIdx.x] = p;
    }
}

// single-block final reduction: sum 2048 float4 partials in f64
__global__ __launch_bounds__(256) void reduce_out(
    const float4* __restrict__ part, float* __restrict__ out)
{
    const int tid  = threadIdx.x;
    const int lane = tid & 63;
    const int wid  = tid >> 6;

    double s0 = 0.0, s1 = 0.0, s2 = 0.0, s3 = 0.0;
    for (int k = tid; k < NPAIRBLK; k += 256) {
        float4 p = part[k];
        s0 += (double)p.x; s1 += (double)p.y;
        s2 += (double)p.z; s3 += (double)p.w;
    }
    #pragma unroll
    for (int off = 32; off > 0; off >>= 1) {
        s0 += __shfl_xor(s0, off, 64);
        s1 += __shfl_xor(s1, off, 64);
        s2 += __shfl_xor(s2, off, 64);
        s3 += __shfl_xor(s3, off, 64);
    }
    __shared__ double sd[4][4];
    if (lane == 0) { sd[wid][0] = s0; sd[wid][1] = s1; sd[wid][2] = s2; sd[wid][3] = s3; }
    __syncthreads();
    if (tid == 0) {
        out[0] = (float)(sd[0][0] + sd[1][0] + sd[2][0] + sd[3][0]);
        out[1] = (float)(sd[0][1] + sd[1][1] + sd[2][1] + sd[3][1]);
        out[2] = (float)(sd[0][2] + sd[1][2] + sd[2][2] + sd[3][2]);
        out[3] = (float)(sd[0][3] + sd[1][3] + sd[2][3] + sd[3][3]);
    }
}

extern "C" void kernel_launch(void* const* d_in, const int* in_sizes, int n_in,
                              void* d_out, int out_size, void* d_ws, size_t ws_size,
                              hipStream_t stream) {
    const int*   S    = (const int*)d_in[0];
    const int*   M    = (const int*)d_in[1];
    const int*   inst = (const int*)d_in[2];
    const float* sims = (const float*)d_in[3];
    const float* Xc   = (const float*)d_in[4];
    const float* Xr   = (const float*)d_in[5];
    const float* Ac   = (const float*)d_in[6];
    const float* Ar   = (const float*)d_in[7];
    float* out = (float*)d_out;

    char* ws = (char*)d_ws;
    signed char* emb_q = (signed char*)(ws);              // 8192*512 int8 = 4 MiB
    float*  bv   = (float*)(ws + 4194304);                // 32 KiB
    float4* part = (float4*)(ws + 4227072);               // 2048*16 B = 32 KiB

    attn_kernel<<<NUM_SETS, 256, 0, stream>>>(S, M, Xc, Xr, Ac, Ar, emb_q, bv);
    pair_kernel<<<NPAIRBLK, 256, 0, stream>>>(inst, sims, emb_q, bv, part);
    reduce_out<<<1, 256, 0, stream>>>(part, out);
}

// Round 11
// 87.415 us; speedup vs baseline: 1.1228x; 1.0799x over previous
//
#include <hip/hip_runtime.h>

#define EPSF 1e-8f
#define DIM 256
#define SET_LEN 50
#define NUM_SETS 8192
#define BATCH 131072

#define LOG2E 1.4426950408889634f
#define LN2   0.6931471805599453f
#define EPS2  1.4426950409e-8f      /* EPSF / LN2 */
#define CPD  -0.5287663729448977f   /* log2(LN2)  */

#define QSCALE 100.0f
#define QINV   0.01f
#define Q2E    (QINV * LOG2E)       /* int-domain -> exp2 argument */
#define LUTOFF 204                  /* q in [-204, 306] -> idx in [0, 510] */
#define LUTSZ  512

#define SSCALE 127.0f               /* LDS row-staging quant scale */
#define SINV   (1.0f / 127.0f)

#define PPW 16                      /* pairs per wave */
#define NPAIRBLK (BATCH / (PPW * 4))  /* 2048 pair blocks */

__device__ __forceinline__ float fast_exp2(float x) {
#if __has_builtin(__builtin_amdgcn_exp2f)
    return __builtin_amdgcn_exp2f(x);
#else
    return exp2f(x);
#endif
}
__device__ __forceinline__ float fast_log2(float x) {
#if __has_builtin(__builtin_amdgcn_logf)
    return __builtin_amdgcn_logf(x);
#else
    return __log2f(x);
#endif
}

// lsp2(x) = log2( log2(1 + 2^(x*log2e)) + EPS2 )
// so that  ln(softplus(x) + EPS) == LN2 * (CPD + lsp2(x))   (exact algebra)
__device__ __forceinline__ float lsp2(float x) {
    float e = fast_exp2(x * LOG2E);
    float s = fast_log2(1.0f + e);
    return fast_log2(s + EPS2);
}
__device__ __forceinline__ float lsp2q(int q) {
    float e = fast_exp2((float)q * Q2E);
    float s = fast_log2(1.0f + e);
    return fast_log2(s + EPS2);
}

__device__ __forceinline__ float wave_reduce_sum(float v) {
    #pragma unroll
    for (int off = 32; off > 0; off >>= 1) v += __shfl_xor(v, off, 64);
    return v;
}
__device__ __forceinline__ float wave_reduce_max(float v) {
    #pragma unroll
    for (int off = 32; off > 0; off >>= 1) v = fmaxf(v, __shfl_xor(v, off, 64));
    return v;
}

__device__ __forceinline__ float dot4(float4 a, float4 b) {
    return a.x*b.x + a.y*b.y + a.z*b.z + a.w*b.w;
}
__device__ __forceinline__ signed char quant8(float v) {
    int q = (int)rintf(v * QSCALE);
    q = max(-127, min(127, q));
    return (signed char)q;
}
__device__ __forceinline__ unsigned int pack_i8x4(float4 v) {
    int a = max(-127, min(127, (int)rintf(v.x * SSCALE)));
    int b = max(-127, min(127, (int)rintf(v.y * SSCALE)));
    int c = max(-127, min(127, (int)rintf(v.z * SSCALE)));
    int d = max(-127, min(127, (int)rintf(v.w * SSCALE)));
    return (unsigned int)(a & 0xff) | ((unsigned int)(b & 0xff) << 8) |
           ((unsigned int)(c & 0xff) << 16) | ((unsigned int)(d & 0xff) << 24);
}

// One block (256 threads) per set. Two-pass: logit pass with 16 lanes/row,
// 4 rows/wave in flight, rows staged to LDS as INT8 (scale 127) -> 26.6 KB
// LDS -> up to 6 blocks/CU. NO min-waves launch bound: R10's (256,6) forced
// VGPR=40 and spilled the 8 in-flight float4 rows to scratch (+45 MB HBM
// traffic, WRITE_SIZE 4.4->37 MB). Let the allocator pick (~85 regs fits
// 6 waves/EU anyway).
__global__ __launch_bounds__(256) void attn_kernel(
    const int* __restrict__ S, const int* __restrict__ M,
    const float* __restrict__ Xc, const float* __restrict__ Xr,
    const float* __restrict__ Ac, const float* __restrict__ Ar,
    signed char* __restrict__ emb_q, float* __restrict__ bv)
{
    const int s    = blockIdx.x;
    const int tid  = threadIdx.x;
    const int lane = tid & 63;
    const int wid  = tid >> 6;
    const int g    = lane >> 4;   // row-group 0..3 within wave
    const int sl   = lane & 15;   // sub-lane 0..15

    __shared__ signed char shc[SET_LEN][DIM];   // 12.8 KB int8 center rows
    __shared__ signed char shr[SET_LEN][DIM];   // 12.8 KB int8 radius rows
    __shared__ int   sh_act[SET_LEN];
    __shared__ float sh_wc[SET_LEN];            // logits, overwritten by weights
    __shared__ float sh_wr[SET_LEN];
    __shared__ int   sh_nact;
    __shared__ float sh_scale;
    __shared__ float sh_red[4];

    // wave 0: load indices/mask, ballot-compact active rows
    if (wid == 0) {
        int idx = 0, m = 0;
        if (lane < SET_LEN) {
            idx = S[s * SET_LEN + lane];
            m   = M[s * SET_LEN + lane];
        }
        unsigned long long bal = __ballot(m != 0);
        int rank = __popcll(bal & ((1ull << lane) - 1ull));
        if (m) sh_act[rank] = idx;
        if (lane == 0) {
            int n = __popcll(bal);
            sh_nact = n;
            sh_scale = (n > 0) ? exp2f(log2f((float)n) * (1.0f / DIM)) : 0.0f;
        }
    }
    __syncthreads();
    const int nact = sh_nact;

    // per-lane A fragments: chunk c covers float4 index c*16+sl
    float4 afc[4], afr[4];
    #pragma unroll
    for (int c = 0; c < 4; ++c) {
        afc[c] = ((const float4*)Ac)[c * 16 + sl];
        afr[c] = ((const float4*)Ar)[c * 16 + sl];
    }

    // logit + stage pass: 16 rows per block-iter (4 waves x 4 groups)
    const int nit = (nact + 15) >> 4;
    for (int it = 0; it < nit; ++it) {
        const int k = it * 16 + wid * 4 + g;
        float pc = 0.0f, pr = 0.0f;
        if (k < nact) {
            const size_t row = (size_t)sh_act[k] * DIM;
            const float4* xc = (const float4*)(Xc + row);
            const float4* xr = (const float4*)(Xr + row);
            float4 c0 = xc[sl], c1 = xc[16 + sl], c2 = xc[32 + sl], c3 = xc[48 + sl];
            float4 r0 = xr[sl], r1 = xr[16 + sl], r2 = xr[32 + sl], r3 = xr[48 + sl];
            pc = dot4(c0, afc[0]) + dot4(c1, afc[1]) + dot4(c2, afc[2]) + dot4(c3, afc[3]);
            pr = dot4(r0, afr[0]) + dot4(r1, afr[1]) + dot4(r2, afr[2]) + dot4(r3, afr[3]);
            // stage rows to LDS as int8 (lane already holds them)
            *(unsigned int*)&shc[k][  0 + 4*sl] = pack_i8x4(c0);
            *(unsigned int*)&shc[k][ 64 + 4*sl] = pack_i8x4(c1);
            *(unsigned int*)&shc[k][128 + 4*sl] = pack_i8x4(c2);
            *(unsigned int*)&shc[k][192 + 4*sl] = pack_i8x4(c3);
            *(unsigned int*)&shr[k][  0 + 4*sl] = pack_i8x4(r0);
            *(unsigned int*)&shr[k][ 64 + 4*sl] = pack_i8x4(r1);
            *(unsigned int*)&shr[k][128 + 4*sl] = pack_i8x4(r2);
            *(unsigned int*)&shr[k][192 + 4*sl] = pack_i8x4(r3);
        }
        #pragma unroll
        for (int off = 8; off > 0; off >>= 1) {
            pc += __shfl_xor(pc, off, 64);
            pr += __shfl_xor(pr, off, 64);
        }
        if (k < nact && sl == 0) { sh_wc[k] = pc; sh_wr[k] = pr; }
    }
    __syncthreads();

    // compacted softmax in-place (logits -> weights): wave0 center, wave1 radius
    if (wid < 2) {
        float* w = (wid == 0) ? sh_wc : sh_wr;
        float v  = (lane < nact) ? w[lane] : -1e30f;
        float mx = wave_reduce_max(v);
        float p  = (lane < nact) ? __expf(v - mx) : 0.0f;
        float sm = wave_reduce_sum(p);
        float inv = (sm > 0.0f) ? (1.0f / sm) : 0.0f;
        if (lane < nact) w[lane] = p * inv;
    }
    __syncthreads();

    // weighted-sum pass entirely from LDS: thread tid owns dim d = tid
    float accc = 0.0f, accr = 0.0f;
    #pragma unroll 4
    for (int k = 0; k < nact; ++k) {
        accc = fmaf(sh_wc[k], (float)shc[k][tid], accc);
        accr = fmaf(sh_wr[k], (float)shr[k][tid], accr);
    }
    const float scale = sh_scale * SINV;   // fold 1/127 dequant into size-scale
    const float ec = accc * scale;
    const float er = accr * scale;
    emb_q[(size_t)s * 512 + tid]       = quant8(ec);
    emb_q[(size_t)s * 512 + 256 + tid] = quant8(er);

    float term = lsp2(er);
    float wsum = wave_reduce_sum(term);
    if (lane == 0) sh_red[wid] = wsum;
    __syncthreads();
    if (tid == 0)
        bv[s] = LN2 * ((sh_red[0] + sh_red[1] + sh_red[2] + sh_red[3])
                       + (float)DIM * CPD);
}

__device__ __forceinline__ void i8x16_unpack(uint4 u, int* o) {
    unsigned int ws[4] = { u.x, u.y, u.z, u.w };
    #pragma unroll
    for (int w = 0; w < 4; ++w) {
        o[4*w+0] = (int)(signed char)(ws[w]);
        o[4*w+1] = (int)(signed char)(ws[w] >> 8);
        o[4*w+2] = (int)(signed char)(ws[w] >> 16);
        o[4*w+3] = (int)(signed char)(ws[w] >> 24);
    }
}

// int-domain box terms for 16 dims, one LDS LUT read per term.
__device__ __forceinline__ void pair_accum_lut(const float* __restrict__ lut,
                                               uint4 ac, uint4 ar, uint4 bc, uint4 br,
                                               float& it, float& ut) {
    int ci[16], ri[16], cj[16], rj[16];
    i8x16_unpack(ac, ci); i8x16_unpack(ar, ri);
    i8x16_unpack(bc, cj); i8x16_unpack(br, rj);
    #pragma unroll
    for (int k = 0; k < 16; ++k) {
        const int Mi = ci[k] + ri[k];
        const int Mj = cj[k] + rj[k];
        const int lo = min(Mi, Mj) - max(ci[k], cj[k]);
        const int hi = max(Mi, Mj) - min(ci[k], cj[k]);
        it += lut[lo + LUTOFF];
        ut += lut[hi + LUTOFF];
    }
}

// 16 lanes per pair, 4 pairs in flight per wave; int8 emb rows, LDS LUT,
// per-block partials (no atomics).
__global__ __launch_bounds__(256) void pair_kernel(
    const int* __restrict__ inst, const float* __restrict__ sims,
    const signed char* __restrict__ emb_q,
    const float* __restrict__ bv, float4* __restrict__ part)
{
    const int tid  = threadIdx.x;
    const int lane = tid & 63;
    const int wid  = tid >> 6;
    const int g    = lane >> 4;
    const int sl   = lane & 15;
    const int wave = blockIdx.x * 4 + wid;
    const int base = wave * PPW;

    __shared__ float lut[LUTSZ];
    __shared__ float sh_i[4][PPW];
    __shared__ float sh_u[4][PPW];
    __shared__ float sred[4][4];

    #pragma unroll
    for (int e = tid; e < LUTSZ; e += 256) lut[e] = lsp2q(e - LUTOFF);

    int idxreg = 0;
    if (lane < 2 * PPW) idxreg = inst[2 * base + lane];
    __syncthreads();

    uint4 a_c, a_r, b_c, b_r;
    {
        const int i = __shfl(idxreg, 2 * g);
        const int j = __shfl(idxreg, 2 * g + 1);
        const uint4* pi = (const uint4*)(emb_q + (size_t)i * 512);
        const uint4* pj = (const uint4*)(emb_q + (size_t)j * 512);
        a_c = pi[sl]; a_r = pi[16 + sl];
        b_c = pj[sl]; b_r = pj[16 + sl];
    }

    #pragma unroll
    for (int m = 0; m < 4; ++m) {
        uint4 n0, n1, n2, n3;
        if (m < 3) {
            const int slot = (m + 1) * 4 + g;
            const int i = __shfl(idxreg, 2 * slot);
            const int j = __shfl(idxreg, 2 * slot + 1);
            const uint4* pi = (const uint4*)(emb_q + (size_t)i * 512);
            const uint4* pj = (const uint4*)(emb_q + (size_t)j * 512);
            n0 = pi[sl]; n1 = pi[16 + sl];
            n2 = pj[sl]; n3 = pj[16 + sl];
        }

        float it = 0.0f, ut = 0.0f;
        pair_accum_lut(lut, a_c, a_r, b_c, b_r, it, ut);
        #pragma unroll
        for (int o = 8; o > 0; o >>= 1) {
            it += __shfl_xor(it, o, 64);
            ut += __shfl_xor(ut, o, 64);
        }
        if (sl == 0) { sh_i[wid][m * 4 + g] = it; sh_u[wid][m * 4 + g] = ut; }

        if (m < 3) { a_c = n0; a_r = n1; b_c = n2; b_r = n3; }
    }
    __syncthreads();

    float l1 = 0.0f, l2 = 0.0f, l3 = 0.0f, l4 = 0.0f;
    if (lane < PPW) {
        const int b = base + lane;
        const int i = inst[2 * b];
        const int j = inst[2 * b + 1];
        const float inter = LN2 * (sh_i[wid][lane] + (float)DIM * CPD);
        const float unn   = LN2 * (sh_u[wid][lane] + (float)DIM * CPD);
        const float bvi = bv[i], bvj = bv[j];
        const float co  = __expf(inter - fmaxf(bvi, bvj));
        const float cja = __expf(inter - unn);
        const float cco = __expf(inter - 0.5f * (bvi + bvj));
        const float cdi = 2.0f * __expf(inter) /
                          (__expf(bvi) + __expf(bvj) + EPSF);
        const float4 sm = ((const float4*)sims)[b];
        float d;
        d = co  - sm.x; l1 = d * d;
        d = cja - sm.y; l2 = d * d;
        d = cco - sm.z; l3 = d * d;
        d = cdi - sm.w; l4 = d * d;
    }
    l1 = wave_reduce_sum(l1);
    l2 = wave_reduce_sum(l2);
    l3 = wave_reduce_sum(l3);
    l4 = wave_reduce_sum(l4);

    if (lane == 0) {
        sred[wid][0] = l1; sred[wid][1] = l2;
        sred[wid][2] = l3; sred[wid][3] = l4;
    }
    __syncthreads();
    if (tid == 0) {
        float4 p;
        p.x = sred[0][0] + sred[1][0] + sred[2][0] + sred[3][0];
        p.y = sred[0][1] + sred[1][1] + sred[2][1] + sred[3][1];
        p.z = sred[0][2] + sred[1][2] + sred[2][2] + sred[3][2];
        p.w = sred[0][3] + sred[1][3] + sred[2][3] + sred[3][3];
        part[blockIdx.x] = p;
    }
}

// single-block final reduction: sum 2048 float4 partials in f64
__global__ __launch_bounds__(256) void reduce_out(
    const float4* __restrict__ part, float* __restrict__ out)
{
    const int tid  = threadIdx.x;
    const int lane = tid & 63;
    const int wid  = tid >> 6;

    double s0 = 0.0, s1 = 0.0, s2 = 0.0, s3 = 0.0;
    for (int k = tid; k < NPAIRBLK; k += 256) {
        float4 p = part[k];
        s0 += (double)p.x; s1 += (double)p.y;
        s2 += (double)p.z; s3 += (double)p.w;
    }
    #pragma unroll
    for (int off = 32; off > 0; off >>= 1) {
        s0 += __shfl_xor(s0, off, 64);
        s1 += __shfl_xor(s1, off, 64);
        s2 += __shfl_xor(s2, off, 64);
        s3 += __shfl_xor(s3, off, 64);
    }
    __shared__ double sd[4][4];
    if (lane == 0) { sd[wid][0] = s0; sd[wid][1] = s1; sd[wid][2] = s2; sd[wid][3] = s3; }
    __syncthreads();
    if (tid == 0) {
        out[0] = (float)(sd[0][0] + sd[1][0] + sd[2][0] + sd[3][0]);
        out[1] = (float)(sd[0][1] + sd[1][1] + sd[2][1] + sd[3][1]);
        out[2] = (float)(sd[0][2] + sd[1][2] + sd[2][2] + sd[3][2]);
        out[3] = (float)(sd[0][3] + sd[1][3] + sd[2][3] + sd[3][3]);
    }
}

extern "C" void kernel_launch(void* const* d_in, const int* in_sizes, int n_in,
                              void* d_out, int out_size, void* d_ws, size_t ws_size,
                              hipStream_t stream) {
    const int*   S    = (const int*)d_in[0];
    const int*   M    = (const int*)d_in[1];
    const int*   inst = (const int*)d_in[2];
    const float* sims = (const float*)d_in[3];
    const float* Xc   = (const float*)d_in[4];
    const float* Xr   = (const float*)d_in[5];
    const float* Ac   = (const float*)d_in[6];
    const float* Ar   = (const float*)d_in[7];
    float* out = (float*)d_out;

    char* ws = (char*)d_ws;
    signed char* emb_q = (signed char*)(ws);              // 8192*512 int8 = 4 MiB
    float*  bv   = (float*)(ws + 4194304);                // 32 KiB
    float4* part = (float4*)(ws + 4227072);               // 2048*16 B = 32 KiB

    attn_kernel<<<NUM_SETS, 256, 0, stream>>>(S, M, Xc, Xr, Ac, Ar, emb_q, bv);
    pair_kernel<<<NPAIRBLK, 256, 0, stream>>>(inst, sims, emb_q, bv, part);
    reduce_out<<<1, 256, 0, stream>>>(part, out);
}

// Round 12
// 86.823 us; speedup vs baseline: 1.1304x; 1.0068x over previous
//
#include <hip/hip_runtime.h>

#define EPSF 1e-8f
#define DIM 256
#define SET_LEN 50
#define NUM_SETS 8192
#define BATCH 131072

#define LOG2E 1.4426950408889634f
#define LN2   0.6931471805599453f
#define EPS2  1.4426950409e-8f      /* EPSF / LN2 */
#define CPD  -0.5287663729448977f   /* log2(LN2)  */

#define QSCALE 100.0f
#define QINV   0.01f
#define Q2E    (QINV * LOG2E)       /* int-domain -> exp2 argument */
#define LUTOFF 204                  /* q in [-204, 306] -> idx in [0, 510] */
#define LUTSZ  512

#define SSCALE 127.0f               /* LDS row-staging quant scale */
#define SINV   (1.0f / 127.0f)

#define PPW 16                      /* pairs per wave */
#define NPAIRBLK (BATCH / (PPW * 4))  /* 2048 pair blocks */

__device__ __forceinline__ float fast_exp2(float x) {
#if __has_builtin(__builtin_amdgcn_exp2f)
    return __builtin_amdgcn_exp2f(x);
#else
    return exp2f(x);
#endif
}
__device__ __forceinline__ float fast_log2(float x) {
#if __has_builtin(__builtin_amdgcn_logf)
    return __builtin_amdgcn_logf(x);
#else
    return __log2f(x);
#endif
}

// lsp2(x) = log2( log2(1 + 2^(x*log2e)) + EPS2 )
// so that  ln(softplus(x) + EPS) == LN2 * (CPD + lsp2(x))   (exact algebra)
__device__ __forceinline__ float lsp2(float x) {
    float e = fast_exp2(x * LOG2E);
    float s = fast_log2(1.0f + e);
    return fast_log2(s + EPS2);
}
__device__ __forceinline__ float lsp2q(int q) {
    float e = fast_exp2((float)q * Q2E);
    float s = fast_log2(1.0f + e);
    return fast_log2(s + EPS2);
}

__device__ __forceinline__ float wave_reduce_sum(float v) {
    #pragma unroll
    for (int off = 32; off > 0; off >>= 1) v += __shfl_xor(v, off, 64);
    return v;
}
__device__ __forceinline__ float wave_reduce_max(float v) {
    #pragma unroll
    for (int off = 32; off > 0; off >>= 1) v = fmaxf(v, __shfl_xor(v, off, 64));
    return v;
}

__device__ __forceinline__ float dot4(float4 a, float4 b) {
    return a.x*b.x + a.y*b.y + a.z*b.z + a.w*b.w;
}
__device__ __forceinline__ signed char quant8(float v) {
    int q = (int)rintf(v * QSCALE);
    q = max(-127, min(127, q));
    return (signed char)q;
}
__device__ __forceinline__ unsigned int pack_i8x4(float4 v) {
    int a = max(-127, min(127, (int)rintf(v.x * SSCALE)));
    int b = max(-127, min(127, (int)rintf(v.y * SSCALE)));
    int c = max(-127, min(127, (int)rintf(v.z * SSCALE)));
    int d = max(-127, min(127, (int)rintf(v.w * SSCALE)));
    return (unsigned int)(a & 0xff) | ((unsigned int)(b & 0xff) << 8) |
           ((unsigned int)(c & 0xff) << 16) | ((unsigned int)(d & 0xff) << 24);
}

// One block (256 threads) per (set, table). Splitting by table halves LDS
// (13.4 KB -> ~8 resident blocks/CU vs 3) and halves the per-block serial
// gather chain, doubling independent load streams per CU. Math per set is
// bit-identical to the fused version. t=0: center, t=1: radius (+bv).
__global__ __launch_bounds__(256) void attn_kernel(
    const int* __restrict__ S, const int* __restrict__ M,
    const float* __restrict__ Xc, const float* __restrict__ Xr,
    const float* __restrict__ Ac, const float* __restrict__ Ar,
    signed char* __restrict__ emb_q, float* __restrict__ bv)
{
    const int blk  = blockIdx.x;
    const int s    = blk >> 1;
    const int t    = blk & 1;
    const int tid  = threadIdx.x;
    const int lane = tid & 63;
    const int wid  = tid >> 6;
    const int g    = lane >> 4;   // row-group 0..3 within wave
    const int sl   = lane & 15;   // sub-lane 0..15

    const float* __restrict__ X = t ? Xr : Xc;
    const float* __restrict__ A = t ? Ar : Ac;

    __shared__ signed char sh[SET_LEN][DIM];    // 12.8 KB int8 rows
    __shared__ int   sh_act[SET_LEN];
    __shared__ float sh_w[SET_LEN];             // logits -> weights in place
    __shared__ int   sh_nact;
    __shared__ float sh_scale;
    __shared__ float sh_red[4];

    // wave 0: load indices/mask, ballot-compact active rows
    if (wid == 0) {
        int idx = 0, m = 0;
        if (lane < SET_LEN) {
            idx = S[s * SET_LEN + lane];
            m   = M[s * SET_LEN + lane];
        }
        unsigned long long bal = __ballot(m != 0);
        int rank = __popcll(bal & ((1ull << lane) - 1ull));
        if (m) sh_act[rank] = idx;
        if (lane == 0) {
            int n = __popcll(bal);
            sh_nact = n;
            sh_scale = (n > 0) ? exp2f(log2f((float)n) * (1.0f / DIM)) : 0.0f;
        }
    }
    __syncthreads();
    const int nact = sh_nact;

    // per-lane A fragments: chunk c covers float4 index c*16+sl
    float4 af[4];
    #pragma unroll
    for (int c = 0; c < 4; ++c) af[c] = ((const float4*)A)[c * 16 + sl];

    // logit + stage pass: 16 rows per block-iter (4 waves x 4 groups)
    const int nit = (nact + 15) >> 4;
    for (int it = 0; it < nit; ++it) {
        const int k = it * 16 + wid * 4 + g;
        float p = 0.0f;
        if (k < nact) {
            const size_t row = (size_t)sh_act[k] * DIM;
            const float4* x = (const float4*)(X + row);
            float4 v0 = x[sl], v1 = x[16 + sl], v2 = x[32 + sl], v3 = x[48 + sl];
            p = dot4(v0, af[0]) + dot4(v1, af[1]) + dot4(v2, af[2]) + dot4(v3, af[3]);
            // stage row to LDS as int8 (lane already holds it)
            *(unsigned int*)&sh[k][  0 + 4*sl] = pack_i8x4(v0);
            *(unsigned int*)&sh[k][ 64 + 4*sl] = pack_i8x4(v1);
            *(unsigned int*)&sh[k][128 + 4*sl] = pack_i8x4(v2);
            *(unsigned int*)&sh[k][192 + 4*sl] = pack_i8x4(v3);
        }
        #pragma unroll
        for (int off = 8; off > 0; off >>= 1)
            p += __shfl_xor(p, off, 64);
        if (k < nact && sl == 0) sh_w[k] = p;
    }
    __syncthreads();

    // compacted softmax in-place (logits -> weights): wave 0
    if (wid == 0) {
        float v  = (lane < nact) ? sh_w[lane] : -1e30f;
        float mx = wave_reduce_max(v);
        float p  = (lane < nact) ? __expf(v - mx) : 0.0f;
        float sm = wave_reduce_sum(p);
        float inv = (sm > 0.0f) ? (1.0f / sm) : 0.0f;
        if (lane < nact) sh_w[lane] = p * inv;
    }
    __syncthreads();

    // weighted-sum pass entirely from LDS: thread tid owns dim d = tid
    float acc = 0.0f;
    #pragma unroll 4
    for (int k = 0; k < nact; ++k)
        acc = fmaf(sh_w[k], (float)sh[k][tid], acc);
    const float e = acc * sh_scale * SINV;  // fold 1/127 dequant into size-scale
    emb_q[(size_t)s * 512 + t * 256 + tid] = quant8(e);

    if (t) {  // radius block also produces the box volume
        float term = lsp2(e);
        float wsum = wave_reduce_sum(term);
        if (lane == 0) sh_red[wid] = wsum;
        __syncthreads();
        if (tid == 0)
            bv[s] = LN2 * ((sh_red[0] + sh_red[1] + sh_red[2] + sh_red[3])
                           + (float)DIM * CPD);
    }
}

__device__ __forceinline__ void i8x16_unpack(uint4 u, int* o) {
    unsigned int ws[4] = { u.x, u.y, u.z, u.w };
    #pragma unroll
    for (int w = 0; w < 4; ++w) {
        o[4*w+0] = (int)(signed char)(ws[w]);
        o[4*w+1] = (int)(signed char)(ws[w] >> 8);
        o[4*w+2] = (int)(signed char)(ws[w] >> 16);
        o[4*w+3] = (int)(signed char)(ws[w] >> 24);
    }
}

// int-domain box terms for 16 dims, one LDS LUT read per term.
__device__ __forceinline__ void pair_accum_lut(const float* __restrict__ lut,
                                               uint4 ac, uint4 ar, uint4 bc, uint4 br,
                                               float& it, float& ut) {
    int ci[16], ri[16], cj[16], rj[16];
    i8x16_unpack(ac, ci); i8x16_unpack(ar, ri);
    i8x16_unpack(bc, cj); i8x16_unpack(br, rj);
    #pragma unroll
    for (int k = 0; k < 16; ++k) {
        const int Mi = ci[k] + ri[k];
        const int Mj = cj[k] + rj[k];
        const int lo = min(Mi, Mj) - max(ci[k], cj[k]);
        const int hi = max(Mi, Mj) - min(ci[k], cj[k]);
        it += lut[lo + LUTOFF];
        ut += lut[hi + LUTOFF];
    }
}

// 16 lanes per pair, 4 pairs in flight per wave; int8 emb rows, LDS LUT,
// per-block partials (no atomics).
__global__ __launch_bounds__(256) void pair_kernel(
    const int* __restrict__ inst, const float* __restrict__ sims,
    const signed char* __restrict__ emb_q,
    const float* __restrict__ bv, float4* __restrict__ part)
{
    const int tid  = threadIdx.x;
    const int lane = tid & 63;
    const int wid  = tid >> 6;
    const int g    = lane >> 4;
    const int sl   = lane & 15;
    const int wave = blockIdx.x * 4 + wid;
    const int base = wave * PPW;

    __shared__ float lut[LUTSZ];
    __shared__ float sh_i[4][PPW];
    __shared__ float sh_u[4][PPW];
    __shared__ float sred[4][4];

    #pragma unroll
    for (int e = tid; e < LUTSZ; e += 256) lut[e] = lsp2q(e - LUTOFF);

    int idxreg = 0;
    if (lane < 2 * PPW) idxreg = inst[2 * base + lane];
    __syncthreads();

    uint4 a_c, a_r, b_c, b_r;
    {
        const int i = __shfl(idxreg, 2 * g);
        const int j = __shfl(idxreg, 2 * g + 1);
        const uint4* pi = (const uint4*)(emb_q + (size_t)i * 512);
        const uint4* pj = (const uint4*)(emb_q + (size_t)j * 512);
        a_c = pi[sl]; a_r = pi[16 + sl];
        b_c = pj[sl]; b_r = pj[16 + sl];
    }

    #pragma unroll
    for (int m = 0; m < 4; ++m) {
        uint4 n0, n1, n2, n3;
        if (m < 3) {
            const int slot = (m + 1) * 4 + g;
            const int i = __shfl(idxreg, 2 * slot);
            const int j = __shfl(idxreg, 2 * slot + 1);
            const uint4* pi = (const uint4*)(emb_q + (size_t)i * 512);
            const uint4* pj = (const uint4*)(emb_q + (size_t)j * 512);
            n0 = pi[sl]; n1 = pi[16 + sl];
            n2 = pj[sl]; n3 = pj[16 + sl];
        }

        float it = 0.0f, ut = 0.0f;
        pair_accum_lut(lut, a_c, a_r, b_c, b_r, it, ut);
        #pragma unroll
        for (int o = 8; o > 0; o >>= 1) {
            it += __shfl_xor(it, o, 64);
            ut += __shfl_xor(ut, o, 64);
        }
        if (sl == 0) { sh_i[wid][m * 4 + g] = it; sh_u[wid][m * 4 + g] = ut; }

        if (m < 3) { a_c = n0; a_r = n1; b_c = n2; b_r = n3; }
    }
    __syncthreads();

    float l1 = 0.0f, l2 = 0.0f, l3 = 0.0f, l4 = 0.0f;
    if (lane < PPW) {
        const int b = base + lane;
        const int i = inst[2 * b];
        const int j = inst[2 * b + 1];
        const float inter = LN2 * (sh_i[wid][lane] + (float)DIM * CPD);
        const float unn   = LN2 * (sh_u[wid][lane] + (float)DIM * CPD);
        const float bvi = bv[i], bvj = bv[j];
        const float co  = __expf(inter - fmaxf(bvi, bvj));
        const float cja = __expf(inter - unn);
        const float cco = __expf(inter - 0.5f * (bvi + bvj));
        const float cdi = 2.0f * __expf(inter) /
                          (__expf(bvi) + __expf(bvj) + EPSF);
        const float4 sm = ((const float4*)sims)[b];
        float d;
        d = co  - sm.x; l1 = d * d;
        d = cja - sm.y; l2 = d * d;
        d = cco - sm.z; l3 = d * d;
        d = cdi - sm.w; l4 = d * d;
    }
    l1 = wave_reduce_sum(l1);
    l2 = wave_reduce_sum(l2);
    l3 = wave_reduce_sum(l3);
    l4 = wave_reduce_sum(l4);

    if (lane == 0) {
        sred[wid][0] = l1; sred[wid][1] = l2;
        sred[wid][2] = l3; sred[wid][3] = l4;
    }
    __syncthreads();
    if (tid == 0) {
        float4 p;
        p.x = sred[0][0] + sred[1][0] + sred[2][0] + sred[3][0];
        p.y = sred[0][1] + sred[1][1] + sred[2][1] + sred[3][1];
        p.z = sred[0][2] + sred[1][2] + sred[2][2] + sred[3][2];
        p.w = sred[0][3] + sred[1][3] + sred[2][3] + sred[3][3];
        part[blockIdx.x] = p;
    }
}

// single-block final reduction: sum 2048 float4 partials in f64
__global__ __launch_bounds__(256) void reduce_out(
    const float4* __restrict__ part, float* __restrict__ out)
{
    const int tid  = threadIdx.x;
    const int lane = tid & 63;
    const int wid  = tid >> 6;

    double s0 = 0.0, s1 = 0.0, s2 = 0.0, s3 = 0.0;
    for (int k = tid; k < NPAIRBLK; k += 256) {
        float4 p = part[k];
        s0 += (double)p.x; s1 += (double)p.y;
        s2 += (double)p.z; s3 += (double)p.w;
    }
    #pragma unroll
    for (int off = 32; off > 0; off >>= 1) {
        s0 += __shfl_xor(s0, off, 64);
        s1 += __shfl_xor(s1, off, 64);
        s2 += __shfl_xor(s2, off, 64);
        s3 += __shfl_xor(s3, off, 64);
    }
    __shared__ double sd[4][4];
    if (lane == 0) { sd[wid][0] = s0; sd[wid][1] = s1; sd[wid][2] = s2; sd[wid][3] = s3; }
    __syncthreads();
    if (tid == 0) {
        out[0] = (float)(sd[0][0] + sd[1][0] + sd[2][0] + sd[3][0]);
        out[1] = (float)(sd[0][1] + sd[1][1] + sd[2][1] + sd[3][1]);
        out[2] = (float)(sd[0][2] + sd[1][2] + sd[2][2] + sd[3][2]);
        out[3] = (float)(sd[0][3] + sd[1][3] + sd[2][3] + sd[3][3]);
    }
}

extern "C" void kernel_launch(void* const* d_in, const int* in_sizes, int n_in,
                              void* d_out, int out_size, void* d_ws, size_t ws_size,
                              hipStream_t stream) {
    const int*   S    = (const int*)d_in[0];
    const int*   M    = (const int*)d_in[1];
    const int*   inst = (const int*)d_in[2];
    const float* sims = (const float*)d_in[3];
    const float* Xc   = (const float*)d_in[4];
    const float* Xr   = (const float*)d_in[5];
    const float* Ac   = (const float*)d_in[6];
    const float* Ar   = (const float*)d_in[7];
    float* out = (float*)d_out;

    char* ws = (char*)d_ws;
    signed char* emb_q = (signed char*)(ws);              // 8192*512 int8 = 4 MiB
    float*  bv   = (float*)(ws + 4194304);                // 32 KiB
    float4* part = (float4*)(ws + 4227072);               // 2048*16 B = 32 KiB

    attn_kernel<<<2 * NUM_SETS, 256, 0, stream>>>(S, M, Xc, Xr, Ac, Ar, emb_q, bv);
    pair_kernel<<<NPAIRBLK, 256, 0, stream>>>(inst, sims, emb_q, bv, part);
    reduce_out<<<1, 256, 0, stream>>>(part, out);
}